// Round 16
// baseline (234.917 us; speedup 1.0000x reference)
//
#include <hip/hip_runtime.h>
#include <hip/hip_bf16.h>

#define SEQ   20
#define PRED  30
#define TSTEPS (SEQ + PRED)
#define PEDS  16384
#define EMB   64
#define RNN   128
#define PB    64
#define NT    512
#define L2E   1.44269504f

typedef _Float16 half8 __attribute__((ext_vector_type(8)));
typedef __attribute__((ext_vector_type(4))) float f32x4;
typedef __attribute__((ext_vector_type(2))) float f32x2;

// Raw barrier: publish LDS writes (lgkmcnt) but leave vmem (B-prefetch) in
// flight. Fences: "memory" clobber blocks IR motion; sched_barrier pins the
// backend scheduler (m214 r263 hazard).
#define RAW_BAR() do {                                          \
    asm volatile("s_waitcnt lgkmcnt(0)" ::: "memory");          \
    __builtin_amdgcn_s_barrier();                               \
    asm volatile("" ::: "memory");                              \
    __builtin_amdgcn_sched_barrier(0);                          \
} while (0)

__device__ __forceinline__ float sigm2(float xp) {
    return __builtin_amdgcn_rcpf(1.f + __builtin_amdgcn_exp2f(-xp));
}
__device__ __forceinline__ float tanh2p(float xp) {
    float r = __builtin_amdgcn_rcpf(__builtin_amdgcn_exp2f(xp + xp) + 1.f);
    return fmaf(-2.f, r, 1.f);
}
__device__ __forceinline__ float tanh2u(float x) {
    float r = __builtin_amdgcn_rcpf(__builtin_amdgcn_exp2f(x * (2.f * L2E)) + 1.f);
    return fmaf(-2.f, r, 1.f);
}

// B fragments (f16, PRESCALED by log2e): idx = ((kt*32 + nt)*64 + l)*8 + i
// nt = g*8 + jt ; row n = g*128 + jt*16 + (l&15) ; k = kt*32 + (l>>4)*8 + i
// ewp[ke][4] = {Wemb[ke][0], Wemb[ke][1], bemb[ke], 0}  (unscaled)
__global__ void prep_kernel(const float* __restrict__ Wih, const float* __restrict__ Whh,
                            const float* __restrict__ Wemb, const float* __restrict__ bemb,
                            _Float16* __restrict__ Bp, float* __restrict__ ewp) {
    int t = blockIdx.x * blockDim.x + threadIdx.x;
    if (t < 64) {
        ewp[t * 4 + 0] = Wemb[t * 2 + 0];
        ewp[t * 4 + 1] = Wemb[t * 2 + 1];
        ewp[t * 4 + 2] = bemb[t];
        ewp[t * 4 + 3] = 0.f;
    }
    if (t >= 6 * 32 * 64 * 8) return;
    int i  = t & 7;
    int l  = (t >> 3) & 63;
    int nt = (t >> 9) & 31;
    int kt = t >> 14;
    int n = (nt >> 3) * RNN + (nt & 7) * 16 + (l & 15);
    int k = kt * 32 + ((l >> 4) << 3) + i;
    float val = (k < EMB) ? Wih[n * EMB + k] : Whh[n * RNN + (k - EMB)];
    Bp[t] = (_Float16)(val * L2E);
}

__global__ __launch_bounds__(NT, 2) void lstm_kernel(
    const float* __restrict__ obs,
    const float* __restrict__ ewp,
    const float* __restrict__ bih,  const float* __restrict__ bhh,
    const _Float16* __restrict__ Bp,
    const float* __restrict__ Wout, const float* __restrict__ bout,
    float* __restrict__ out)
{
    __shared__ __align__(16) char smA[2 * 24576];   // 48 KB A dbuf (e+h f16)
    __shared__ __align__(16) char smB[2 * 32768];   // 64 KB B dbuf
    __shared__ float smEW[64 * 4];                  // embedding weights
    __shared__ float smWO[256];                     // Wout [o][j]
    __shared__ float outs[64 * 2];

    const int tid = threadIdx.x;
    const int l   = tid & 63;
    const int w   = __builtin_amdgcn_readfirstlane(tid >> 6);  // wave 0..7 (= jt)
    const int pg  = blockIdx.x * PB + l;

    for (int r = tid; r < (2 * 24576) / 4; r += NT) ((int*)smA)[r] = 0;
    if (tid < 64) *(f32x4*)(smEW + tid * 4) = *(const f32x4*)(ewp + tid * 4);
    if (tid < 256) smWO[tid] = Wout[tid];

    const int jlane = w * 16 + (l & 15);
    const int lrow  = (l >> 4) << 2;
    const int swz   = (l & 7) << 4;

    float bias[4];
#pragma unroll
    for (int g = 0; g < 4; ++g) {
        int n = g * RNN + jlane;
        bias[g] = (bih[n] + bhh[n]) * L2E;
    }

    // ---- step-invariant addresses ----
    int aBase[4];
#pragma unroll
    for (int mt = 0; mt < 4; ++mt) {
        int ped = mt * 16 + (l & 15);
        aBase[mt] = ped * 384 + ((l >> 4) << 4);
    }
    int sAddr[4];
#pragma unroll
    for (int r = 0; r < 4; ++r) {
        int ped = lrow + r;
        sAddr[r] = (ped * 384 + 128 + jlane * 2) ^ ((ped & 7) << 4);
    }
    const int eAddr = (l * 384 + w * 16) ^ swz;
    const char* bb  = smB + l * 16;
    const char* stageSrc = (const char*)Bp + l * 16 + w * 1024;

    // O-phase constants: 4 lanes per (ped, o)
    const int oid  = l >> 2, oq = l & 3;
    const int oped = (w << 3) + (oid >> 1);
    const int oo   = oid & 1;
    const float boutv = bout[oo];
    int oOff[4];
#pragma unroll
    for (int t = 0; t < 4; ++t)
        oOff[t] = (oped * 384 + 128 + (oq * 32 + t * 8) * 2) ^ ((oped & 7) << 4);
    const float* woBase = smWO + oo * 128 + oq * 32;

    auto stage = [&](int kt, int buf) {
#pragma unroll
        for (int g = 0; g < 4; ++g) {
            const void* src = stageSrc + kt * 32768 + g * 8192;
            __builtin_amdgcn_global_load_lds(
                (const __attribute__((address_space(1))) void*)src,
                (__attribute__((address_space(3))) void*)(smB + buf * 32768 + (g * 8 + w) * 1024),
                16, 0, 0);
        }
    };

    float c[16];
#pragma unroll
    for (int q = 0; q < 16; ++q) c[q] = 0.f;

    stage(0, 0);
    __syncthreads();  // init publish (drains prologue stage — once)

    const float* xptr = obs + (size_t)pg * 2;
    f32x2 xv = *(const f32x2*)xptr;   // step 0 obs
    xptr += PEDS * 2;
    int curOff = 0;

    for (int step = 0; step < TSTEPS; ++step) {
        const int nxtOff = curOff ^ 24576;

        // ---- E: e = relu(x @ Wemb.T + bemb) -> A[cur] k=0..63
        {
            float x0, x1;
            if (step < SEQ) { x0 = xv[0]; x1 = xv[1]; }
            else            { x0 = outs[l * 2 + 0]; x1 = outs[l * 2 + 1]; }
            half8 vh;
#pragma unroll
            for (int q = 0; q < 8; ++q) {
                const f32x4 ew = *(const f32x4*)(smEW + (w * 8 + q) * 4);
                float v = fmaf(x0, ew[0], fmaf(x1, ew[1], ew[2]));
                vh[q] = (_Float16)fmaxf(v, 0.f);
            }
            *(half8*)(smA + curOff + eAddr) = vh;
        }
        // prefetch next step's obs (issued before G's stages -> oldest in queue,
        // retired by G's vmcnt(4) chain without draining the B prefetch)
        if (step + 1 < SEQ) {
            xv = *(const f32x2*)xptr;
            xptr += PEDS * 2;
        }
        RAW_BAR();  // B1: e(step) + h(step-1) visible

        // ---- G: gates = A @ B + bias' ; f16 1-pass, 6 kt phases
        f32x4 acc[4][4];
#pragma unroll
        for (int mt = 0; mt < 4; ++mt)
#pragma unroll
            for (int g = 0; g < 4; ++g) {
                acc[mt][g][0] = bias[g]; acc[mt][g][1] = bias[g];
                acc[mt][g][2] = bias[g]; acc[mt][g][3] = bias[g];
            }
#pragma unroll
        for (int kt = 0; kt < 6; ++kt) {
            const int buf = kt & 1;
            const int ktn = (kt < 5) ? kt + 1 : 0;
            stage(ktn, buf ^ 1);
            asm volatile("s_waitcnt vmcnt(4)" ::: "memory");
            half8 bf[4];
#pragma unroll
            for (int g = 0; g < 4; ++g)
                bf[g] = *(const half8*)(bb + buf * 32768 + (g * 8 + w) * 1024);
#pragma unroll
            for (int mt = 0; mt < 4; ++mt) {
                half8 ah = *(const half8*)(smA + curOff + ((aBase[mt] + kt * 64) ^ swz));
#pragma unroll
                for (int g = 0; g < 4; ++g)
                    acc[mt][g] = __builtin_amdgcn_mfma_f32_16x16x32_f16(ah, bf[g], acc[mt][g], 0, 0, 0);
            }
        }
        // no barrier: S writes A[nxt], lagging G reads A[cur]

        // ---- S: nonlinearities (prescaled) + c/h update; h -> A[nxt]
#pragma unroll
        for (int mt = 0; mt < 4; ++mt) {
#pragma unroll
            for (int r = 0; r < 4; ++r) {
                float gi = acc[mt][0][r], gf = acc[mt][1][r];
                float gg = acc[mt][2][r], go = acc[mt][3][r];
                float i_ = sigm2(gi), f_ = sigm2(gf), g_ = tanh2p(gg), o_ = sigm2(go);
                float cn = fmaf(f_, c[mt * 4 + r], i_ * g_);
                c[mt * 4 + r] = cn;
                float hn = o_ * tanh2u(cn);
                *(_Float16*)(smA + nxtOff + sAddr[r] + mt * 6144) = (_Float16)hn;
            }
        }

        // ---- O: out = h @ Wout.T + bout ; 4 lanes/(ped,o), shuffle-reduce
        if (step >= SEQ - 1) {
            RAW_BAR();  // h(step) visible
            float s = 0.f;
#pragma unroll
            for (int t = 0; t < 4; ++t) {
                half8 hh8 = *(const half8*)(smA + nxtOff + oOff[t]);
                const f32x4 w0 = *(const f32x4*)(woBase + t * 8);
                const f32x4 w1 = *(const f32x4*)(woBase + t * 8 + 4);
#pragma unroll
                for (int i = 0; i < 4; ++i) {
                    s = fmaf((float)hh8[i], w0[i], s);
                    s = fmaf((float)hh8[i + 4], w1[i], s);
                }
            }
            s += __shfl_xor(s, 1);
            s += __shfl_xor(s, 2);
            if (oq == 0) {
                float ov = s + boutv;
                outs[oped * 2 + oo] = ov;
                if (step >= SEQ)
                    out[((size_t)(step - SEQ) * PEDS + blockIdx.x * PB + oped) * 2 + oo] = ov;
            }
            RAW_BAR();  // outs visible for next E
        }
        curOff = nxtOff;
    }
}

extern "C" void kernel_launch(void* const* d_in, const int* in_sizes, int n_in,
                              void* d_out, int out_size, void* d_ws, size_t ws_size,
                              hipStream_t stream) {
    const float* obs  = (const float*)d_in[0];
    const float* Wemb = (const float*)d_in[1];
    const float* bemb = (const float*)d_in[2];
    const float* Wih  = (const float*)d_in[3];
    const float* bih  = (const float*)d_in[4];
    const float* Whh  = (const float*)d_in[5];
    const float* bhh  = (const float*)d_in[6];
    const float* Wout = (const float*)d_in[7];
    const float* bout = (const float*)d_in[8];

    _Float16* Bp  = (_Float16*)d_ws;                 // 98304 f16 = 192 KB
    float*    ewp = (float*)(Bp + 6 * 32 * 64 * 8);  // 64*4 f32 = 1 KB

    prep_kernel<<<(6 * 32 * 64 * 8 + 255) / 256, 256, 0, stream>>>(Wih, Whh, Wemb, bemb, Bp, ewp);
    lstm_kernel<<<PEDS / PB, NT, 0, stream>>>(obs, ewp, bih, bhh, Bp, Wout, bout, (float*)d_out);
}

// Round 17
// 228.370 us; speedup vs baseline: 1.0287x; 1.0287x over previous
//
#include <hip/hip_runtime.h>
#include <hip/hip_bf16.h>

#define SEQ   20
#define PRED  30
#define TSTEPS (SEQ + PRED)
#define PEDS  16384
#define EMB   64
#define RNN   128
#define PB    64
#define NT    512
#define L2E   1.44269504f

typedef _Float16 half8 __attribute__((ext_vector_type(8)));
typedef __attribute__((ext_vector_type(4))) float f32x4;
typedef __attribute__((ext_vector_type(2))) float f32x2;

// Raw barrier: publish LDS writes (lgkmcnt) but leave vmem (B-prefetch) in flight.
#define RAW_BAR() do {                                          \
    asm volatile("s_waitcnt lgkmcnt(0)" ::: "memory");          \
    __builtin_amdgcn_s_barrier();                               \
    asm volatile("" ::: "memory");                              \
    __builtin_amdgcn_sched_barrier(0);                          \
} while (0)

__device__ __forceinline__ float sigm2(float xp) {
    return __builtin_amdgcn_rcpf(1.f + __builtin_amdgcn_exp2f(-xp));
}
__device__ __forceinline__ float tanh2p(float xp) {
    float r = __builtin_amdgcn_rcpf(__builtin_amdgcn_exp2f(xp + xp) + 1.f);
    return fmaf(-2.f, r, 1.f);
}
__device__ __forceinline__ float tanh2u(float x) {
    float r = __builtin_amdgcn_rcpf(__builtin_amdgcn_exp2f(x * (2.f * L2E)) + 1.f);
    return fmaf(-2.f, r, 1.f);
}

// B fragments (f16, PRESCALED by log2e): idx = ((kt*32 + nt)*64 + l)*8 + i
// nt = g*8 + jt ; row n = g*128 + jt*16 + (l&15) ; k = kt*32 + (l>>4)*8 + i
// ewp[ke][4] = {Wemb[ke][0], Wemb[ke][1], bemb[ke], 0}  (unscaled)
__global__ void prep_kernel(const float* __restrict__ Wih, const float* __restrict__ Whh,
                            const float* __restrict__ Wemb, const float* __restrict__ bemb,
                            _Float16* __restrict__ Bp, float* __restrict__ ewp) {
    int t = blockIdx.x * blockDim.x + threadIdx.x;
    if (t < 64) {
        ewp[t * 4 + 0] = Wemb[t * 2 + 0];
        ewp[t * 4 + 1] = Wemb[t * 2 + 1];
        ewp[t * 4 + 2] = bemb[t];
        ewp[t * 4 + 3] = 0.f;
    }
    if (t >= 6 * 32 * 64 * 8) return;
    int i  = t & 7;
    int l  = (t >> 3) & 63;
    int nt = (t >> 9) & 31;
    int kt = t >> 14;
    int n = (nt >> 3) * RNN + (nt & 7) * 16 + (l & 15);
    int k = kt * 32 + ((l >> 4) << 3) + i;
    float val = (k < EMB) ? Wih[n * EMB + k] : Whh[n * RNN + (k - EMB)];
    Bp[t] = (_Float16)(val * L2E);
}

__global__ __launch_bounds__(NT, 2) void lstm_kernel(
    const float* __restrict__ obs,
    const float* __restrict__ ewp,
    const float* __restrict__ bih,  const float* __restrict__ bhh,
    const _Float16* __restrict__ Bp,
    const float* __restrict__ Wout, const float* __restrict__ bout,
    float* __restrict__ out)
{
    __shared__ __align__(16) char smA[2 * 24576];    // 48 KB A dbuf (e+h f16)
    __shared__ __align__(16) char smB[3 * 32768];    // 96 KB B triple-buf
    __shared__ float smObs[SEQ * 128];               // 10 KB this block's obs
    __shared__ float smEW[64 * 4];                   // embedding weights
    __shared__ float smWO[256];                      // Wout [o][j]
    __shared__ float part[64 * 2 * 4];               // 2 KB
    __shared__ float outs[64 * 2];

    const int tid = threadIdx.x;
    const int l   = tid & 63;
    const int w   = __builtin_amdgcn_readfirstlane(tid >> 6);  // wave 0..7 (= jt)

    for (int r = tid; r < (2 * 24576) / 4; r += NT) ((int*)smA)[r] = 0;
    if (tid < 64) *(f32x4*)(smEW + tid * 4) = *(const f32x4*)(ewp + tid * 4);
    if (tid < 256) smWO[tid] = Wout[tid];
    // obs slab: smObs[step*128 + r] = obs[step*PEDS*2 + blockIdx*128 + r]
    for (int i = tid; i < SEQ * 128; i += NT) {
        int st = i >> 7, r = i & 127;
        smObs[i] = obs[(size_t)st * (PEDS * 2) + blockIdx.x * 128 + r];
    }

    const int jlane = w * 16 + (l & 15);
    const int lrow  = (l >> 4) << 2;
    const int swz   = (l & 7) << 4;

    float bias[4];
#pragma unroll
    for (int g = 0; g < 4; ++g) {
        int n = g * RNN + jlane;
        bias[g] = (bih[n] + bhh[n]) * L2E;
    }

    // ---- step-invariant addresses ----
    int aBase[4];
#pragma unroll
    for (int mt = 0; mt < 4; ++mt) {
        int ped = mt * 16 + (l & 15);
        aBase[mt] = ped * 384 + ((l >> 4) << 4);
    }
    int sAddr[4];
#pragma unroll
    for (int r = 0; r < 4; ++r) {
        int ped = lrow + r;
        sAddr[r] = (ped * 384 + 128 + jlane * 2) ^ ((ped & 7) << 4);
    }
    const int eAddr = (l * 384 + w * 16) ^ swz;
    const int oBase = l * 384 + 128 + (w >> 1) * 64;
    const char* bb  = smB + l * 16;
    const char* stageSrc = (const char*)Bp + l * 16 + w * 1024;
    const float* woBase = smWO + (w & 1) * 128 + (w >> 1) * 32;

    // stage slice (0..5) into buf slice%3: wave stages exactly the 4 frags it reads
    auto stage = [&](int slice) {
        const int buf = slice % 3;
#pragma unroll
        for (int g = 0; g < 4; ++g) {
            const void* src = stageSrc + slice * 32768 + g * 8192;
            __builtin_amdgcn_global_load_lds(
                (const __attribute__((address_space(1))) void*)src,
                (__attribute__((address_space(3))) void*)(smB + buf * 32768 + (g * 8 + w) * 1024),
                16, 0, 0);
        }
    };

    float c[16];
#pragma unroll
    for (int q = 0; q < 16; ++q) c[q] = 0.f;

    stage(0);
    stage(1);
    __syncthreads();  // one-time full drain: slices 0,1 + obs/EW/WO/A-zero published

    int curOff = 0;

    for (int step = 0; step < TSTEPS; ++step) {
        const int nxtOff = curOff ^ 24576;

        // ---- E: e = relu(x @ Wemb.T + bemb) -> A[cur] k=0..63 (all from LDS)
        {
            float x0, x1;
            if (step < SEQ) {
                f32x2 xv = *(const f32x2*)(smObs + step * 128 + l * 2);
                x0 = xv[0]; x1 = xv[1];
            } else {
                x0 = outs[l * 2 + 0];
                x1 = outs[l * 2 + 1];
            }
            half8 vh;
#pragma unroll
            for (int q = 0; q < 8; ++q) {
                const f32x4 ew = *(const f32x4*)(smEW + (w * 8 + q) * 4);
                float v = fmaf(x0, ew[0], fmaf(x1, ew[1], ew[2]));
                vh[q] = (_Float16)fmaxf(v, 0.f);
            }
            *(half8*)(smA + curOff + eAddr) = vh;
        }
        RAW_BAR();  // B1: e(step) + h(step-1) visible; B-prefetch stays in flight

        // ---- G: gates = A @ B + bias' ; f16 1-pass; depth-2 staged pipeline
        f32x4 acc[4][4];
#pragma unroll
        for (int mt = 0; mt < 4; ++mt)
#pragma unroll
            for (int g = 0; g < 4; ++g) {
                acc[mt][g][0] = bias[g]; acc[mt][g][1] = bias[g];
                acc[mt][g][2] = bias[g]; acc[mt][g][3] = bias[g];
            }
#pragma unroll
        for (int kt = 0; kt < 6; ++kt) {
            const int buf = kt % 3;
            stage((kt < 4) ? kt + 2 : kt - 4);  // depth-2; kt>=4 stages next step's slices
            // slice kt's 4 loads are 8 deep (kt-1's 4 + kt's 4 are newer)
            asm volatile("s_waitcnt vmcnt(8)" ::: "memory");
            half8 bf[4];
#pragma unroll
            for (int g = 0; g < 4; ++g)
                bf[g] = *(const half8*)(bb + buf * 32768 + (g * 8 + w) * 1024);
#pragma unroll
            for (int mt = 0; mt < 4; ++mt) {
                half8 ah = *(const half8*)(smA + curOff + ((aBase[mt] + kt * 64) ^ swz));
#pragma unroll
                for (int g = 0; g < 4; ++g)
                    acc[mt][g] = __builtin_amdgcn_mfma_f32_16x16x32_f16(ah, bf[g], acc[mt][g], 0, 0, 0);
            }
        }
        // no barrier: S writes A[nxt], lagging G reads A[cur]

        // ---- S: nonlinearities (prescaled) + c/h update; h -> A[nxt]
#pragma unroll
        for (int mt = 0; mt < 4; ++mt) {
#pragma unroll
            for (int r = 0; r < 4; ++r) {
                float gi = acc[mt][0][r], gf = acc[mt][1][r];
                float gg = acc[mt][2][r], go = acc[mt][3][r];
                float i_ = sigm2(gi), f_ = sigm2(gf), g_ = tanh2p(gg), o_ = sigm2(go);
                float cn = fmaf(f_, c[mt * 4 + r], i_ * g_);
                c[mt * 4 + r] = cn;
                float hn = o_ * tanh2u(cn);
                *(_Float16*)(smA + nxtOff + sAddr[r] + mt * 6144) = (_Float16)hn;
            }
        }

        // ---- O: out = h @ Wout.T + bout (part[]-reduced, Wout from LDS)
        if (step >= SEQ - 1) {
            RAW_BAR();  // h(step) visible
            {
                const int oo = w & 1;
                float s = 0.f;
#pragma unroll
                for (int t = 0; t < 4; ++t) {
                    half8 hh8 = *(const half8*)(smA + nxtOff + ((oBase + t * 16) ^ swz));
                    const f32x4 w0 = *(const f32x4*)(woBase + t * 8);
                    const f32x4 w1 = *(const f32x4*)(woBase + t * 8 + 4);
#pragma unroll
                    for (int i = 0; i < 4; ++i) {
                        s = fmaf((float)hh8[i], w0[i], s);
                        s = fmaf((float)hh8[i + 4], w1[i], s);
                    }
                }
                part[(l * 2 + oo) * 4 + (w >> 1)] = s;
            }
            RAW_BAR();
            if (tid < 128) {
                int pp = tid & 63, o2 = tid >> 6;
                const float* pr = &part[(pp * 2 + o2) * 4];
                float o = bout[o2] + ((pr[0] + pr[1]) + (pr[2] + pr[3]));
                outs[pp * 2 + o2] = o;
                if (step >= SEQ)
                    out[((size_t)(step - SEQ) * PEDS + blockIdx.x * PB + pp) * 2 + o2] = o;
            }
            RAW_BAR();  // outs visible for next E
        }
        curOff = nxtOff;
    }
}

extern "C" void kernel_launch(void* const* d_in, const int* in_sizes, int n_in,
                              void* d_out, int out_size, void* d_ws, size_t ws_size,
                              hipStream_t stream) {
    const float* obs  = (const float*)d_in[0];
    const float* Wemb = (const float*)d_in[1];
    const float* bemb = (const float*)d_in[2];
    const float* Wih  = (const float*)d_in[3];
    const float* bih  = (const float*)d_in[4];
    const float* Whh  = (const float*)d_in[5];
    const float* bhh  = (const float*)d_in[6];
    const float* Wout = (const float*)d_in[7];
    const float* bout = (const float*)d_in[8];

    _Float16* Bp  = (_Float16*)d_ws;                 // 98304 f16 = 192 KB
    float*    ewp = (float*)(Bp + 6 * 32 * 64 * 8);  // 64*4 f32 = 1 KB

    prep_kernel<<<(6 * 32 * 64 * 8 + 255) / 256, 256, 0, stream>>>(Wih, Whh, Wemb, bemb, Bp, ewp);
    lstm_kernel<<<PEDS / PB, NT, 0, stream>>>(obs, ewp, bih, bhh, Bp, Wout, bout, (float*)d_out);
}